// Round 2
// baseline (550.057 us; speedup 1.0000x reference)
//
#include <hip/hip_runtime.h>

// Problem constants (fixed by the reference): 131072 rows x 512 dims, 10 classes.
#define NROWS   131072
#define DIMS    512
#define NC      10
#define SEG_BLOCKS 512        // 256 rows per block, 1024 threads (16 waves)
#define SUMSTRIDE 5120        // 10*512 floats per partial copy

typedef __attribute__((ext_vector_type(8))) short short8;   // 8 bf16 in 4 VGPRs
typedef __attribute__((ext_vector_type(4))) float floatx4;

// ---- helpers -------------------------------------------------------------

static __device__ __forceinline__ unsigned int pk2(float lo, float hi) {
    // pack two fp32 -> two bf16 (truncation; abs error 4.0 vs threshold 13.5)
    return (__float_as_uint(hi) & 0xFFFF0000u) | (__float_as_uint(lo) >> 16);
}

static __device__ __forceinline__ short8 pack8(const float4 a, const float4 b) {
    union { unsigned int u[4]; short8 v; } r;
    r.u[0] = pk2(a.x, a.y);
    r.u[1] = pk2(a.z, a.w);
    r.u[2] = pk2(b.x, b.y);
    r.u[3] = pk2(b.z, b.w);
    return r.v;
}

// ---- kernel 1: per-block segment sums (register acc + LDS-atomic merge) --
// 512 blocks x 1024 threads. part8 = tid>>7 (8 row-phases), dt = tid&127
// (dim chunk, 4 floats). Thread covers rows rows0 + 8i + part8, i<32.
// Merge: ds_add_f32 into red[k][c][dt] (bank-conflict-free: addr%32 == dt%32),
// class-staggered by part8 so no two part-groups hit the same address burst.
// Output: plain coalesced 20KB store per block. No global atomics, no memset.

__global__ __launch_bounds__(1024, 4) void k_seg(const float* __restrict__ E,
                                                 const int* __restrict__ L,
                                                 float* __restrict__ part,
                                                 int* __restrict__ counts) {
    __shared__ float red[4 * NC * 128];   // 20 KB, layout [k][c][dt]
    __shared__ int lc[16];
    const int tid   = threadIdx.x;
    const int part8 = tid >> 7;
    const int dt    = tid & 127;
    for (int j = tid; j < 4 * NC * 128; j += 1024) red[j] = 0.f;
    if (tid < 16) lc[tid] = 0;
    __syncthreads();

    const int rows0 = blockIdx.x * 256;
    const float4* Ev = (const float4*)E;

    float4 z = {0.f, 0.f, 0.f, 0.f};
    float4 a0=z,a1=z,a2=z,a3=z,a4=z,a5=z,a6=z,a7=z,a8=z,a9=z;

    int idx = (rows0 + part8) * 128 + dt;
    float4 v = Ev[idx];
    int lab = L[rows0 + part8];

    for (int i = 0; i < 32; ++i) {
        float4 vn = v; int ln = lab;
        if (i < 31) {                        // depth-2 prefetch (next row-phase)
            vn = Ev[idx + 1024];
            ln = L[rows0 + 8 * i + 8 + part8];
            idx += 1024;
        }
        if (dt == 0) atomicAdd(&lc[lab], 1);  // 8 counting lanes x 32 rows = 256
        switch (lab) {                         // lab is wave-uniform -> scalar branch
            case 0: a0.x+=v.x; a0.y+=v.y; a0.z+=v.z; a0.w+=v.w; break;
            case 1: a1.x+=v.x; a1.y+=v.y; a1.z+=v.z; a1.w+=v.w; break;
            case 2: a2.x+=v.x; a2.y+=v.y; a2.z+=v.z; a2.w+=v.w; break;
            case 3: a3.x+=v.x; a3.y+=v.y; a3.z+=v.z; a3.w+=v.w; break;
            case 4: a4.x+=v.x; a4.y+=v.y; a4.z+=v.z; a4.w+=v.w; break;
            case 5: a5.x+=v.x; a5.y+=v.y; a5.z+=v.z; a5.w+=v.w; break;
            case 6: a6.x+=v.x; a6.y+=v.y; a6.z+=v.z; a6.w+=v.w; break;
            case 7: a7.x+=v.x; a7.y+=v.y; a7.z+=v.z; a7.w+=v.w; break;
            case 8: a8.x+=v.x; a8.y+=v.y; a8.z+=v.z; a8.w+=v.w; break;
            default: a9.x+=v.x; a9.y+=v.y; a9.z+=v.z; a9.w+=v.w; break;
        }
        v = vn; lab = ln;
    }

    // LDS-atomic merge, class-staggered iteration order per part-group
    for (int j = 0; j < 10; ++j) {
        int c = j + part8; if (c >= 10) c -= 10;   // wave-uniform
        float4 ac;
        switch (c) {
            case 0: ac = a0; break; case 1: ac = a1; break;
            case 2: ac = a2; break; case 3: ac = a3; break;
            case 4: ac = a4; break; case 5: ac = a5; break;
            case 6: ac = a6; break; case 7: ac = a7; break;
            case 8: ac = a8; break; default: ac = a9; break;
        }
        atomicAdd(&red[0 * 1280 + c * 128 + dt], ac.x);
        atomicAdd(&red[1 * 1280 + c * 128 + dt], ac.y);
        atomicAdd(&red[2 * 1280 + c * 128 + dt], ac.z);
        atomicAdd(&red[3 * 1280 + c * 128 + dt], ac.w);
    }
    __syncthreads();

    float* dst = part + blockIdx.x * SUMSTRIDE;
    for (int j = tid; j < SUMSTRIDE; j += 1024) dst[j] = red[j];
    if (tid < 16) counts[blockIdx.x * 16 + tid] = lc[tid];
}

// ---- kernel 2: reduce 512 partial copies -> 8 partial copies -------------
// 320 blocks = 40 col-chunks x 8 copy-chunks; each block: 128 cols x 64 copies.

__global__ __launch_bounds__(256) void k_red(const float* __restrict__ part,
                                             float* __restrict__ psum8) {
    __shared__ float m[128];
    const int t   = threadIdx.x;
    const int col = t & 127, kh = t >> 7;
    const int cc  = blockIdx.x % 40;
    const int kc  = blockIdx.x / 40;
    const int e   = cc * 128 + col;

    const float* base = part + (size_t)(kc * 64 + kh * 32) * SUMSTRIDE + e;
    float s0=0.f, s1=0.f, s2=0.f, s3=0.f;
    for (int j = 0; j < 32; j += 4) {        // 4-way ILP
        s0 += base[(j + 0) * SUMSTRIDE];
        s1 += base[(j + 1) * SUMSTRIDE];
        s2 += base[(j + 2) * SUMSTRIDE];
        s3 += base[(j + 3) * SUMSTRIDE];
    }
    float s = (s0 + s1) + (s2 + s3);
    if (kh) m[col] = s;
    __syncthreads();
    if (!kh) psum8[kc * SUMSTRIDE + e] = s + m[col];
}

// ---- kernel 3: prototypes + ||p||^2 + zero loss (single block) -----------
// psum8 element order is [k][c][dt] (k = d&3, dt = d>>2) from k_seg's layout.

__global__ __launch_bounds__(512) void k_pp(const float* __restrict__ psum8,
                                            const int* __restrict__ counts,
                                            float* __restrict__ p2,
                                            float* __restrict__ pn,
                                            float* __restrict__ out) {
    __shared__ float P[16 * DIMS];   // 32 KB
    __shared__ int tmp[512];
    __shared__ int cnt[16];
    const int t = threadIdx.x;

    // counts: 512 copies x 16 -> cnt[16]
    {
        const int c0 = t & 15, chunk = t >> 4;   // 32 chunks of 16 copies
        int s = 0;
        for (int j = 0; j < 16; ++j) s += counts[(chunk * 16 + j) * 16 + c0];
        tmp[t] = s;
    }
    __syncthreads();
    if (t < 16) {
        int n = 0;
        for (int ch = 0; ch < 32; ++ch) n += tmp[ch * 16 + t];
        cnt[t] = n;
    }
    if (t == 0) out[0] = 0.f;                    // loss accumulator
    __syncthreads();

    for (int e = t; e < 16 * DIMS; e += 512) {   // p2 = 2*prototype, zero-padded
        const int c = e >> 9, d = e & 511;
        float val = 0.f;
        if (c < NC) {
            const int e2 = (d & 3) * 1280 + c * 128 + (d >> 2);
            float s = 0.f;
#pragma unroll
            for (int j = 0; j < 8; ++j) s += psum8[j * SUMSTRIDE + e2];
            val = 2.f * s / (float)cnt[c];
        }
        p2[e] = val;
        P[e] = val;
    }
    __syncthreads();

    const int w = t >> 6, lane = t & 63;
    const float4* Pv = (const float4*)P;
    for (int sdx = 0; sdx < 2; ++sdx) {
        const int c = w + sdx * 8;               // covers 0..15
        float4 a = Pv[c * 128 + lane * 2];
        float4 b = Pv[c * 128 + lane * 2 + 1];
        float ss = a.x*a.x + a.y*a.y + a.z*a.z + a.w*a.w
                 + b.x*b.x + b.y*b.y + b.z*b.z + b.w*b.w;
        ss += __shfl_xor(ss, 1);  ss += __shfl_xor(ss, 2);
        ss += __shfl_xor(ss, 4);  ss += __shfl_xor(ss, 8);
        ss += __shfl_xor(ss, 16); ss += __shfl_xor(ss, 32);
        if (lane == 0) pn[c] = 0.25f * ss;       // p2 = 2p -> /4
    }
}

// ---- kernel 4: distances + logits + log-softmax + loss -------------------
// One wave per 16-row tile; MFMA 16x16x32 bf16 for the 2*e.p cross term.
// A-frag: lane holds row (lane&15), k = (lane>>4)*8 + j   [verified layout]
// C/D:    lane holds col (lane&15), rows (lane>>4)*4 + reg [verified layout]
// unroll 4 + launch_bounds(256,3): keep VGPRs ~<=170 (bf[16]=64 + 4-deep
// load window) so occupancy stays >=3 waves/SIMD — full unroll spilled.

__global__ __launch_bounds__(256, 3) void k_main(const float* __restrict__ E,
                                                 const int* __restrict__ L,
                                                 const float* __restrict__ p2,
                                                 const float* __restrict__ pn,
                                                 float* __restrict__ out) {
    const int tid  = threadIdx.x;
    const int wid  = tid >> 6, lane = tid & 63;
    const int c16  = lane & 15, quad = lane >> 4;

    // B fragments (prototypes as bf16), built once per wave: 64 VGPRs
    short8 bf[16];
    const float4* P = (const float4*)p2;
#pragma unroll
    for (int kt = 0; kt < 16; ++kt) {
        float4 a = P[c16 * 128 + kt * 8 + quad * 2];
        float4 b = P[c16 * 128 + kt * 8 + quad * 2 + 1];
        bf[kt] = pack8(a, b);
    }
    const float pnc = pn[c16];

    float lossp = 0.f;
    const int gw = blockIdx.x * 4 + wid;            // 0..4095
    for (int t = gw; t < 8192; t += 4096) {
        const int tile  = 8191 - t;                 // reverse order: L3-friendly vs k_seg
        const int rbase = tile * 16;
        const float4* A = (const float4*)(E + (size_t)(rbase + c16) * DIMS);

        floatx4 acc = {0.f, 0.f, 0.f, 0.f};
        float nrm = 0.f;
#pragma unroll 4
        for (int kt = 0; kt < 16; ++kt) {
            float4 a = A[kt * 8 + quad * 2];
            float4 b = A[kt * 8 + quad * 2 + 1];
            nrm += a.x*a.x + a.y*a.y + a.z*a.z + a.w*a.w;
            nrm += b.x*b.x + b.y*b.y + b.z*b.z + b.w*b.w;
            acc = __builtin_amdgcn_mfma_f32_16x16x32_bf16(pack8(a, b), bf[kt],
                                                          acc, 0, 0, 0);
        }
        // full ||e_row||^2 for row (lane&15): sum the 4 k-phases
        nrm += __shfl_xor(nrm, 16);
        nrm += __shfl_xor(nrm, 32);

#pragma unroll
        for (int i = 0; i < 4; ++i) {
            const int row = rbase + quad * 4 + i;
            const float nr = __shfl(nrm, quad * 4 + i);   // lane r holds norm of row r
            float lg = acc[i] - nr - pnc;                  // = 2e.p - ||e||^2 - ||p||^2 = -d2
            lg = fminf(lg, 0.f);                           // reference clamps d2 >= 0
            float ml = (c16 < NC) ? lg : -3.0e38f;
            ml = fmaxf(ml, __shfl_xor(ml, 1));
            ml = fmaxf(ml, __shfl_xor(ml, 2));
            ml = fmaxf(ml, __shfl_xor(ml, 4));
            ml = fmaxf(ml, __shfl_xor(ml, 8));
            float ex = (c16 < NC) ? __expf(lg - ml) : 0.f;
            ex += __shfl_xor(ex, 1);
            ex += __shfl_xor(ex, 2);
            ex += __shfl_xor(ex, 4);
            ex += __shfl_xor(ex, 8);
            const float lse = ml + __logf(ex);
            if (c16 < NC) out[1 + row * NC + c16] = lg;
            const int lab = L[row];
            if (c16 == lab) lossp += lse - lg;
        }
    }

    lossp += __shfl_xor(lossp, 1);  lossp += __shfl_xor(lossp, 2);
    lossp += __shfl_xor(lossp, 4);  lossp += __shfl_xor(lossp, 8);
    lossp += __shfl_xor(lossp, 16); lossp += __shfl_xor(lossp, 32);
    __shared__ float ls[4];
    if (lane == 0) ls[wid] = lossp;
    __syncthreads();
    if (tid == 0)
        atomicAdd(out, (ls[0] + ls[1] + ls[2] + ls[3]) * (1.0f / (float)NROWS));
}

// ---- launch --------------------------------------------------------------

extern "C" void kernel_launch(void* const* d_in, const int* in_sizes, int n_in,
                              void* d_out, int out_size, void* d_ws, size_t ws_size,
                              hipStream_t stream) {
    const float* E = (const float*)d_in[0];
    const int*   L = (const int*)d_in[1];
    float* out = (float*)d_out;
    char* ws = (char*)d_ws;

    // ws layout (bytes):
    //   part   512*5120*4 = 10485760   @ 0
    //   psum8    8*5120*4 =   163840   @ 10485760
    //   counts  512*16*4  =    32768   @ 10649600
    //   p2     16*512*4   =    32768   @ 10682368
    //   pn     16*4       =       64   @ 10715136
    float* part   = (float*)ws;
    float* psum8  = (float*)(ws + 10485760);
    int*   counts = (int*)  (ws + 10649600);
    float* p2     = (float*)(ws + 10682368);
    float* pn     = (float*)(ws + 10715136);

    k_seg <<<SEG_BLOCKS, 1024, 0, stream>>>(E, L, part, counts);
    k_red <<<320,         256, 0, stream>>>(part, psum8);
    k_pp  <<<1,           512, 0, stream>>>(psum8, counts, p2, pn, out);
    k_main<<<1024,        256, 0, stream>>>(E, L, p2, pn, out);
}

// Round 3
// 453.287 us; speedup vs baseline: 1.2135x; 1.2135x over previous
//
#include <hip/hip_runtime.h>

// Problem constants (fixed by the reference): 131072 rows x 512 dims, 10 classes.
#define NROWS   131072
#define DIMS    512
#define NC      10
#define SEG_BLOCKS 1024       // 128 rows per block, 256 threads (4 waves)
#define SUMSTRIDE 5120        // 10*512 floats per partial copy

typedef __attribute__((ext_vector_type(8))) short short8;   // 8 bf16 in 4 VGPRs
typedef __attribute__((ext_vector_type(4))) float floatx4;

// ---- helpers -------------------------------------------------------------

static __device__ __forceinline__ unsigned int pk2(float lo, float hi) {
    // pack two fp32 -> two bf16 (truncation; abs error 4.0 vs threshold 13.5)
    return (__float_as_uint(hi) & 0xFFFF0000u) | (__float_as_uint(lo) >> 16);
}

static __device__ __forceinline__ short8 pack8(const float4 a, const float4 b) {
    union { unsigned int u[4]; short8 v; } r;
    r.u[0] = pk2(a.x, a.y);
    r.u[1] = pk2(a.z, a.w);
    r.u[2] = pk2(b.x, b.y);
    r.u[3] = pk2(b.z, b.w);
    return r.v;
}

// ---- kernel 1: per-block segment sums ------------------------------------
// 1024 blocks x 256 threads. half = tid>>7, dt = tid&127. Thread covers dims
// [4dt,4dt+4) of rows rows0 + 2i + half, i<64. Register accumulators with
// ALL-STATIC indexing (round-2 lesson: any dynamic index over a0..a9 demotes
// them to scratch -> 200us). Depth-3 pipeline: 2 outstanding loads/wave.
// Merge via LDS (plain store/add, static per-class), coalesced partial store.

__global__ __launch_bounds__(256) void k_seg(const float* __restrict__ E,
                                             const int* __restrict__ L,
                                             float* __restrict__ part,
                                             int* __restrict__ counts) {
    __shared__ float4 R[NC * 128];   // 20 KB merge buffer
    __shared__ int lc[16];
    const int tid  = threadIdx.x;
    const int half = tid >> 7;
    const int dt   = tid & 127;
    if (tid < 16) lc[tid] = 0;
    __syncthreads();

    const int rows0 = blockIdx.x * 128;
    const float4* Ev = (const float4*)E;

    float4 z = {0.f, 0.f, 0.f, 0.f};
    float4 a0=z,a1=z,a2=z,a3=z,a4=z,a5=z,a6=z,a7=z,a8=z,a9=z;

    int idx = (rows0 + half) * 128 + dt;       // row stride 2 => +256 float4
    float4 v0 = Ev[idx];
    float4 v1 = Ev[idx + 256];
    int l0 = L[rows0 + half];
    int l1 = L[rows0 + 2 + half];

    for (int i = 0; i < 64; ++i) {
        float4 v2; int l2;
        const bool pf = (i < 62);
        if (pf) {                               // prefetch 2 rows ahead
            v2 = Ev[idx + 512];
            l2 = L[rows0 + 2 * i + 4 + half];
        }
        if (dt == 0) atomicAdd(&lc[l0], 1);     // 2 lanes x 64 iters = 128 rows
        switch (l0) {                           // wave-uniform -> scalar branch
            case 0: a0.x+=v0.x; a0.y+=v0.y; a0.z+=v0.z; a0.w+=v0.w; break;
            case 1: a1.x+=v0.x; a1.y+=v0.y; a1.z+=v0.z; a1.w+=v0.w; break;
            case 2: a2.x+=v0.x; a2.y+=v0.y; a2.z+=v0.z; a2.w+=v0.w; break;
            case 3: a3.x+=v0.x; a3.y+=v0.y; a3.z+=v0.z; a3.w+=v0.w; break;
            case 4: a4.x+=v0.x; a4.y+=v0.y; a4.z+=v0.z; a4.w+=v0.w; break;
            case 5: a5.x+=v0.x; a5.y+=v0.y; a5.z+=v0.z; a5.w+=v0.w; break;
            case 6: a6.x+=v0.x; a6.y+=v0.y; a6.z+=v0.z; a6.w+=v0.w; break;
            case 7: a7.x+=v0.x; a7.y+=v0.y; a7.z+=v0.z; a7.w+=v0.w; break;
            case 8: a8.x+=v0.x; a8.y+=v0.y; a8.z+=v0.z; a8.w+=v0.w; break;
            default: a9.x+=v0.x; a9.y+=v0.y; a9.z+=v0.z; a9.w+=v0.w; break;
        }
        v0 = v1; l0 = l1;
        if (pf) { v1 = v2; l1 = l2; }
        idx += 256;
    }

    // static LDS merge: half-1 stores, half-0 adds + writes partials
    if (half) {
        R[0*128+dt]=a0; R[1*128+dt]=a1; R[2*128+dt]=a2; R[3*128+dt]=a3;
        R[4*128+dt]=a4; R[5*128+dt]=a5; R[6*128+dt]=a6; R[7*128+dt]=a7;
        R[8*128+dt]=a8; R[9*128+dt]=a9;
    }
    __syncthreads();
    if (!half) {
        float4* dst = (float4*)(part + (size_t)blockIdx.x * SUMSTRIDE);
        float4 t;
#define MERGE_ST(c, ac)                                                       \
        t = R[(c)*128 + dt];                                                  \
        t.x += ac.x; t.y += ac.y; t.z += ac.z; t.w += ac.w;                   \
        dst[(c)*128 + dt] = t;
        MERGE_ST(0,a0) MERGE_ST(1,a1) MERGE_ST(2,a2) MERGE_ST(3,a3)
        MERGE_ST(4,a4) MERGE_ST(5,a5) MERGE_ST(6,a6) MERGE_ST(7,a7)
        MERGE_ST(8,a8) MERGE_ST(9,a9)
#undef MERGE_ST
    }
    if (tid < 16) counts[blockIdx.x * 16 + tid] = lc[tid];
}

// ---- kernel 2: reduce 1024 partial copies -> 8 partial copies ------------
// 320 blocks = 40 col-chunks x 8 copy-chunks; each block: 128 cols x 128 copies.

__global__ __launch_bounds__(256) void k_red(const float* __restrict__ part,
                                             float* __restrict__ psum8) {
    __shared__ float m[128];
    const int t   = threadIdx.x;
    const int col = t & 127, kh = t >> 7;
    const int cc  = blockIdx.x % 40;
    const int kc  = blockIdx.x / 40;
    const int e   = cc * 128 + col;

    const float* base = part + (size_t)(kc * 128 + kh * 64) * SUMSTRIDE + e;
    float s0=0.f, s1=0.f, s2=0.f, s3=0.f;
    for (int j = 0; j < 64; j += 4) {        // 4-way ILP over 64 copies
        s0 += base[(size_t)(j + 0) * SUMSTRIDE];
        s1 += base[(size_t)(j + 1) * SUMSTRIDE];
        s2 += base[(size_t)(j + 2) * SUMSTRIDE];
        s3 += base[(size_t)(j + 3) * SUMSTRIDE];
    }
    float s = (s0 + s1) + (s2 + s3);
    if (kh) m[col] = s;
    __syncthreads();
    if (!kh) psum8[kc * SUMSTRIDE + e] = s + m[col];
}

// ---- kernel 3: prototypes + ||p||^2 + zero loss (single block) -----------
// part/psum8 element order is [c][dim] (from k_seg's R layout).

__global__ __launch_bounds__(512) void k_pp(const float* __restrict__ psum8,
                                            const int* __restrict__ counts,
                                            float* __restrict__ p2,
                                            float* __restrict__ pn,
                                            float* __restrict__ out) {
    __shared__ float P[16 * DIMS];   // 32 KB
    __shared__ int tmp[512];
    __shared__ int cnt[16];
    const int t = threadIdx.x;

    // counts: 1024 copies x 16 -> cnt[16]
    {
        const int c0 = t & 15, chunk = t >> 4;   // 32 chunks x 32 copies
        int s = 0;
        for (int j = 0; j < 32; ++j) s += counts[(chunk * 32 + j) * 16 + c0];
        tmp[t] = s;
    }
    __syncthreads();
    if (t < 16) {
        int n = 0;
        for (int ch = 0; ch < 32; ++ch) n += tmp[ch * 16 + t];
        cnt[t] = n;
    }
    if (t == 0) out[0] = 0.f;                    // loss accumulator
    __syncthreads();

    for (int e = t; e < 16 * DIMS; e += 512) {   // p2 = 2*prototype, zero-padded
        const int c = e >> 9;
        float val = 0.f;
        if (c < NC) {
            float s = 0.f;
#pragma unroll
            for (int j = 0; j < 8; ++j) s += psum8[j * SUMSTRIDE + e];
            val = 2.f * s / (float)cnt[c];
        }
        p2[e] = val;
        P[e] = val;
    }
    __syncthreads();

    const int w = t >> 6, lane = t & 63;
    const float4* Pv = (const float4*)P;
    for (int sdx = 0; sdx < 2; ++sdx) {
        const int c = w + sdx * 8;               // covers 0..15
        float4 a = Pv[c * 128 + lane * 2];
        float4 b = Pv[c * 128 + lane * 2 + 1];
        float ss = a.x*a.x + a.y*a.y + a.z*a.z + a.w*a.w
                 + b.x*b.x + b.y*b.y + b.z*b.z + b.w*b.w;
        ss += __shfl_xor(ss, 1);  ss += __shfl_xor(ss, 2);
        ss += __shfl_xor(ss, 4);  ss += __shfl_xor(ss, 8);
        ss += __shfl_xor(ss, 16); ss += __shfl_xor(ss, 32);
        if (lane == 0) pn[c] = 0.25f * ss;       // p2 = 2p -> /4
    }
}

// ---- kernel 4: distances + logits + log-softmax + loss -------------------
// One wave per 16-row tile; MFMA 16x16x32 bf16 for the 2*e.p cross term.
// A-frag: lane holds row (lane&15), k = (lane>>4)*8 + j   [verified layout]
// C/D:    lane holds col (lane&15), rows (lane>>4)*4 + reg [verified layout]
// FULL unroll: bf[kt] must be statically indexed (round-2 lesson) or the
// 64-VGPR bf array is demoted to scratch. launch_bounds(256,2): no spills.

__global__ __launch_bounds__(256, 2) void k_main(const float* __restrict__ E,
                                                 const int* __restrict__ L,
                                                 const float* __restrict__ p2,
                                                 const float* __restrict__ pn,
                                                 float* __restrict__ out) {
    const int tid  = threadIdx.x;
    const int wid  = tid >> 6, lane = tid & 63;
    const int c16  = lane & 15, quad = lane >> 4;

    // B fragments (prototypes as bf16), built once per wave: 64 VGPRs
    short8 bf[16];
    const float4* P = (const float4*)p2;
#pragma unroll
    for (int kt = 0; kt < 16; ++kt) {
        float4 a = P[c16 * 128 + kt * 8 + quad * 2];
        float4 b = P[c16 * 128 + kt * 8 + quad * 2 + 1];
        bf[kt] = pack8(a, b);
    }
    const float pnc = pn[c16];

    float lossp = 0.f;
    const int gw = blockIdx.x * 4 + wid;            // 0..4095
    for (int t = gw; t < 8192; t += 4096) {
        const int tile  = 8191 - t;                 // reverse order: L3-friendly vs k_seg
        const int rbase = tile * 16;
        const float4* A = (const float4*)(E + (size_t)(rbase + c16) * DIMS);

        floatx4 acc = {0.f, 0.f, 0.f, 0.f};
        float nrm = 0.f;
#pragma unroll
        for (int kt = 0; kt < 16; ++kt) {
            float4 a = A[kt * 8 + quad * 2];
            float4 b = A[kt * 8 + quad * 2 + 1];
            nrm += a.x*a.x + a.y*a.y + a.z*a.z + a.w*a.w;
            nrm += b.x*b.x + b.y*b.y + b.z*b.z + b.w*b.w;
            acc = __builtin_amdgcn_mfma_f32_16x16x32_bf16(pack8(a, b), bf[kt],
                                                          acc, 0, 0, 0);
        }
        // full ||e_row||^2 for row (lane&15): sum the 4 k-phases
        nrm += __shfl_xor(nrm, 16);
        nrm += __shfl_xor(nrm, 32);

#pragma unroll
        for (int i = 0; i < 4; ++i) {
            const int row = rbase + quad * 4 + i;
            const float nr = __shfl(nrm, quad * 4 + i);   // lane r holds norm of row r
            float lg = acc[i] - nr - pnc;                  // = 2e.p - ||e||^2 - ||p||^2 = -d2
            lg = fminf(lg, 0.f);                           // reference clamps d2 >= 0
            float ml = (c16 < NC) ? lg : -3.0e38f;
            ml = fmaxf(ml, __shfl_xor(ml, 1));
            ml = fmaxf(ml, __shfl_xor(ml, 2));
            ml = fmaxf(ml, __shfl_xor(ml, 4));
            ml = fmaxf(ml, __shfl_xor(ml, 8));
            float ex = (c16 < NC) ? __expf(lg - ml) : 0.f;
            ex += __shfl_xor(ex, 1);
            ex += __shfl_xor(ex, 2);
            ex += __shfl_xor(ex, 4);
            ex += __shfl_xor(ex, 8);
            const float lse = ml + __logf(ex);
            if (c16 < NC) out[1 + row * NC + c16] = lg;
            const int lab = L[row];
            if (c16 == lab) lossp += lse - lg;
        }
    }

    lossp += __shfl_xor(lossp, 1);  lossp += __shfl_xor(lossp, 2);
    lossp += __shfl_xor(lossp, 4);  lossp += __shfl_xor(lossp, 8);
    lossp += __shfl_xor(lossp, 16); lossp += __shfl_xor(lossp, 32);
    __shared__ float ls[4];
    if (lane == 0) ls[wid] = lossp;
    __syncthreads();
    if (tid == 0)
        atomicAdd(out, (ls[0] + ls[1] + ls[2] + ls[3]) * (1.0f / (float)NROWS));
}

// ---- launch --------------------------------------------------------------

extern "C" void kernel_launch(void* const* d_in, const int* in_sizes, int n_in,
                              void* d_out, int out_size, void* d_ws, size_t ws_size,
                              hipStream_t stream) {
    const float* E = (const float*)d_in[0];
    const int*   L = (const int*)d_in[1];
    float* out = (float*)d_out;
    char* ws = (char*)d_ws;

    // ws layout (bytes):
    //   part   1024*5120*4 = 20971520   @ 0
    //   psum8     8*5120*4 =   163840   @ 20971520
    //   counts 1024*16*4   =    65536   @ 21135360
    //   p2     16*512*4    =    32768   @ 21200896
    //   pn     16*4        =       64   @ 21233664
    float* part   = (float*)ws;
    float* psum8  = (float*)(ws + 20971520);
    int*   counts = (int*)  (ws + 21135360);
    float* p2     = (float*)(ws + 21200896);
    float* pn     = (float*)(ws + 21233664);

    k_seg <<<SEG_BLOCKS, 256, 0, stream>>>(E, L, part, counts);
    k_red <<<320,        256, 0, stream>>>(part, psum8);
    k_pp  <<<1,          512, 0, stream>>>(psum8, counts, p2, pn, out);
    k_main<<<1024,       256, 0, stream>>>(E, L, p2, pn, out);
}